// Round 12
// baseline (1847.422 us; speedup 1.0000x reference)
//
#include <hip/hip_runtime.h>

#define NN   100000
#define NE   3200000
#define INF_ 512
#define HIDF 64
#define OUTF 16
#define BR    128                       // bucket = 128 consecutive dst nodes
#define NBUCK ((NN + BR - 1) / BR)      // 782
#define EBLK  16384                     // edges per fillA/bhist block
#define NFB   ((NE + EBLK - 1) / EBLK)  // 196

typedef __bf16 bf16x8 __attribute__((ext_vector_type(8)));
typedef float  f32x4  __attribute__((ext_vector_type(4)));

__device__ inline unsigned short f2bfu(float f) {      // RNE fp32 -> bf16 bits
    unsigned u = __builtin_bit_cast(unsigned, f);
    u += 0x7FFFu + ((u >> 16) & 1u);
    return (unsigned short)(u >> 16);
}
__device__ inline __bf16 bfbits(unsigned short h) {
    return __builtin_bit_cast(__bf16, h);
}
__device__ inline float bf2f(unsigned short h) {
    unsigned u = (unsigned)h << 16;
    return __builtin_bit_cast(float, u);
}

// ------------------------------------------------------- bucket histogram --
__global__ __launch_bounds__(256) void k_bhist(const int* __restrict__ dst,
                                               int* __restrict__ bcnt) {
    __shared__ int hist[NBUCK];
    int t = threadIdx.x;
    int e0 = blockIdx.x * EBLK;
    int e1 = (e0 + EBLK < NE) ? e0 + EBLK : NE;
    for (int b = t; b < NBUCK; b += 256) hist[b] = 0;
    __syncthreads();
    for (int e = e0 + t; e < e1; e += 256)
        atomicAdd(&hist[dst[e] >> 7], 1);
    __syncthreads();
    for (int b = t; b < NBUCK; b += 256) {
        int c = hist[b];
        if (c) atomicAdd(&bcnt[b], c);
    }
}

// ----------------------------------------------- bucket scan (one block) ---
__global__ __launch_bounds__(256) void k_bscan(const int* __restrict__ bcnt,
                                               int* __restrict__ bbase,
                                               int* __restrict__ bcur) {
    __shared__ int lds[256];
    int t = threadIdx.x;
    int base = t * 4;
    int c[4];
#pragma unroll
    for (int i = 0; i < 4; ++i) { int idx = base + i; c[i] = idx < NBUCK ? bcnt[idx] : 0; }
    int tsum = c[0] + c[1] + c[2] + c[3];
    lds[t] = tsum;
    __syncthreads();
    for (int off = 1; off < 256; off <<= 1) {
        int v = lds[t];
        int a = (t >= off) ? lds[t - off] : 0;
        __syncthreads();
        lds[t] = v + a;
        __syncthreads();
    }
    int pre = (t == 0) ? 0 : lds[t - 1];
    int run = pre;
#pragma unroll
    for (int i = 0; i < 4; ++i) {
        int idx = base + i;
        if (idx < NBUCK) { bbase[idx] = run; bcur[idx] = run; }
        run += c[i];
    }
    if (t == 255) bbase[NBUCK] = lds[255];   // == NE
}

// -------------------------------------------------- bucketed pair fill -----
// Block-local histogram + bulk reservation; packed pair = (src<<7)|(dst&127).
__global__ __launch_bounds__(256) void k_fillA(const int* __restrict__ src,
                                               const int* __restrict__ dst,
                                               int* __restrict__ bcur,
                                               unsigned int* __restrict__ pairs) {
    __shared__ int hist[NBUCK];
    __shared__ int rbase[NBUCK];
    int t = threadIdx.x;
    int e0 = blockIdx.x * EBLK;
    int e1 = (e0 + EBLK < NE) ? e0 + EBLK : NE;

    for (int b = t; b < NBUCK; b += 256) hist[b] = 0;
    __syncthreads();
    for (int e = e0 + t; e < e1; e += 256)
        atomicAdd(&hist[dst[e] >> 7], 1);
    __syncthreads();
    for (int b = t; b < NBUCK; b += 256) {
        int c = hist[b];
        rbase[b] = c ? atomicAdd(&bcur[b], c) : 0;
        hist[b] = 0;
    }
    __syncthreads();
    for (int e = e0 + t; e < e1; e += 256) {
        int s = src[e], d = dst[e];
        int b = d >> 7;
        int slot = atomicAdd(&hist[b], 1);
        pairs[rbase[b] + slot] = ((unsigned)s << 7) | (unsigned)(d & 127);
    }
}

// ---------------------------------------------------- per-node degrees -----
__global__ __launch_bounds__(256) void k_deg(const int* __restrict__ bbase,
                                             const unsigned int* __restrict__ pairs,
                                             float* __restrict__ dinv) {
    __shared__ int cnt[BR];
    int t = threadIdx.x, b = blockIdx.x, n0 = b * BR;
    if (t < BR) cnt[t] = 0;
    __syncthreads();
    int gbase = bbase[b], gend = bbase[b + 1];
    for (int j = gbase + t; j < gend; j += 256)
        atomicAdd(&cnt[pairs[j] & 127u], 1);
    __syncthreads();
    if (t < BR && n0 + t < NN) dinv[n0 + t] = rsqrtf((float)(cnt[t] + 1));
}

// ---------------------------------------------------------------- GEMM1 -----
// h1b (bf16) = x @ W1 via MFMA 16x16x32 bf16. 4 waves, 64 nodes/block.
#define GM 64

__global__ __launch_bounds__(256) void k_gemm1(const float* __restrict__ x,
                                               const float* __restrict__ W1,
                                               unsigned short* __restrict__ h1b) {
    __shared__ unsigned short w1b[INF_ * 66];   // 66 KB
    int t = threadIdx.x;

#pragma unroll
    for (int i = 0; i < 32; ++i) {
        int fidx = t + i * 256;
        int k  = fidx >> 4;
        int n4 = (fidx & 15) * 4;
        float4 v = *(const float4*)&W1[(size_t)k * HIDF + n4];
        ushort4 u;
        u.x = f2bfu(v.x); u.y = f2bfu(v.y); u.z = f2bfu(v.z); u.w = f2bfu(v.w);
        *(ushort4*)&w1b[k * 66 + n4] = u;
    }
    __syncthreads();

    int lane = t & 63;
    int w    = t >> 6;
    int m    = lane & 15;
    int kg   = lane >> 4;
    int mb   = blockIdx.x * GM;

    int rowi = mb + w * 16 + m;
    size_t xrow = (size_t)((rowi < NN) ? rowi : NN - 1);
    const float* xp = x + xrow * INF_ + kg * 4;

    f32x4 acc0 = {0.f,0.f,0.f,0.f}, acc1 = acc0, acc2 = acc0, acc3 = acc0;

#pragma unroll 2
    for (int ks = 0; ks < 16; ++ks) {
        float4 xa = *(const float4*)(xp + ks * 32);
        float4 xb = *(const float4*)(xp + ks * 32 + 16);
        bf16x8 A;
        A[0] = bfbits(f2bfu(xa.x)); A[1] = bfbits(f2bfu(xa.y));
        A[2] = bfbits(f2bfu(xa.z)); A[3] = bfbits(f2bfu(xa.w));
        A[4] = bfbits(f2bfu(xb.x)); A[5] = bfbits(f2bfu(xb.y));
        A[6] = bfbits(f2bfu(xb.z)); A[7] = bfbits(f2bfu(xb.w));

        const unsigned short* wr = &w1b[(ks * 32 + kg * 4) * 66 + m];
#pragma unroll
        for (int n0t = 0; n0t < 4; ++n0t) {
            const unsigned short* wn = wr + n0t * 16;
            bf16x8 B;
            B[0] = bfbits(wn[0]);        B[1] = bfbits(wn[66]);
            B[2] = bfbits(wn[132]);      B[3] = bfbits(wn[198]);
            B[4] = bfbits(wn[16 * 66]);  B[5] = bfbits(wn[17 * 66]);
            B[6] = bfbits(wn[18 * 66]);  B[7] = bfbits(wn[19 * 66]);
            f32x4 c = (n0t == 0) ? acc0 : (n0t == 1) ? acc1 : (n0t == 2) ? acc2 : acc3;
            c = __builtin_amdgcn_mfma_f32_16x16x32_bf16(A, B, c, 0, 0, 0);
            if      (n0t == 0) acc0 = c;
            else if (n0t == 1) acc1 = c;
            else if (n0t == 2) acc2 = c;
            else               acc3 = c;
        }
    }

#pragma unroll
    for (int r = 0; r < 4; ++r) {
        int node = mb + w * 16 + kg * 4 + r;
        if (node < NN) {
            size_t o = (size_t)node * HIDF + m;
            h1b[o +  0] = f2bfu(acc0[r]);
            h1b[o + 16] = f2bfu(acc1[r]);
            h1b[o + 32] = f2bfu(acc2[r]);
            h1b[o + 48] = f2bfu(acc3[r]);
        }
    }
}

// --------------------- layer1 aggregate + ReLU + GEMM2, bucket-local -------
// One block per bucket. Edges: gather h1b[src]*dinv[src] -> LDS f32 atomics.
// Then self-loop+bias+ReLU in LDS, then h2 = hid @ W2 (W2 staged in LDS).
#define AST 65   // padded acc stride (kills k%32 bank conflict in gemm2 phase)

__global__ __launch_bounds__(256) void k_agg1(const int* __restrict__ bbase,
                                              const unsigned int* __restrict__ pairs,
                                              const float* __restrict__ dinv,
                                              const unsigned short* __restrict__ h1b,
                                              const float* __restrict__ b1,
                                              const float* __restrict__ W2,
                                              float* __restrict__ h2) {
    __shared__ float acc[BR * AST];      // 33.3 KB
    __shared__ float w2s[HIDF * OUTF];   // 4 KB
    __shared__ float b1s[HIDF];
    int t = threadIdx.x;
    int b = blockIdx.x;
    int n0 = b * BR;
    int gbase = bbase[b], gend = bbase[b + 1];

    for (int i = t; i < BR * AST; i += 256) acc[i] = 0.f;
    for (int i = t; i < HIDF * OUTF; i += 256) w2s[i] = W2[i];
    if (t < HIDF) b1s[t] = b1[t];
    __syncthreads();

    int w  = t >> 6;     // wave 0..3
    int l  = t & 63;
    int g  = l >> 4;     // edge slot within wave
    int l4 = l & 15;     // feat quad: covers feats l4*4..+3

    for (int base = gbase + w * 4; base < gend; base += 16) {
        int idx = base + g;
        if (idx < gend) {
            unsigned p = pairs[idx];
            int doff = (int)(p & 127u);
            int src  = (int)(p >> 7);
            float ds = dinv[src];
            ushort4 hv = *(const ushort4*)&h1b[(size_t)src * HIDF + l4 * 4];
            float* ar = &acc[doff * AST + l4 * 4];
            atomicAdd(&ar[0], bf2f(hv.x) * ds);
            atomicAdd(&ar[1], bf2f(hv.y) * ds);
            atomicAdd(&ar[2], bf2f(hv.z) * ds);
            atomicAdd(&ar[3], bf2f(hv.w) * ds);
        }
    }
    __syncthreads();

    // self-loop + bias + ReLU (in place)
    for (int i = t; i < BR * HIDF; i += 256) {
        int no = i >> 6, f = i & 63;
        int node = n0 + no;
        if (node < NN) {
            float dn = dinv[node];
            float v = acc[no * AST + f] + dn * bf2f(h1b[(size_t)node * HIDF + f]);
            acc[no * AST + f] = fmaxf(fmaf(dn, v, b1s[f]), 0.f);
        }
    }
    __syncthreads();

    // fused GEMM2: h2[node][o] = hid[node][:] . W2[:][o]
    for (int i = t; i < BR * OUTF; i += 256) {
        int no = i >> 4, o = i & 15;
        int node = n0 + no;
        if (node < NN) {
            const float* ar = &acc[no * AST];
            float s = 0.f;
#pragma unroll 8
            for (int k = 0; k < HIDF; ++k)
                s = fmaf(ar[k], w2s[k * OUTF + o], s);
            h2[(size_t)node * OUTF + o] = s;
        }
    }
}

// --------------- layer2 aggregate + bias + log_softmax, bucket-local -------
#define A2 17

__global__ __launch_bounds__(256) void k_agg2(const int* __restrict__ bbase,
                                              const unsigned int* __restrict__ pairs,
                                              const float* __restrict__ dinv,
                                              const float* __restrict__ h2,
                                              const float* __restrict__ b2,
                                              float* __restrict__ out) {
    __shared__ float acc[BR * A2];   // 8.7 KB
    int t = threadIdx.x;
    int b = blockIdx.x;
    int n0 = b * BR;
    int gbase = bbase[b], gend = bbase[b + 1];

    for (int i = t; i < BR * A2; i += 256) acc[i] = 0.f;
    __syncthreads();

    int w = t >> 6, l = t & 63, g = l >> 4, f = l & 15;
    for (int base = gbase + w * 4; base < gend; base += 16) {
        int idx = base + g;
        if (idx < gend) {
            unsigned p = pairs[idx];
            int doff = (int)(p & 127u);
            int src  = (int)(p >> 7);
            atomicAdd(&acc[doff * A2 + f], h2[(size_t)src * OUTF + f] * dinv[src]);
        }
    }
    __syncthreads();

    // self-loop + bias + log_softmax (16 lanes per node)
#pragma unroll
    for (int pass = 0; pass < 8; ++pass) {
        int no = pass * 16 + (t >> 4);
        int o  = t & 15;
        int node = n0 + no;
        if (node < NN) {
            float dn = dinv[node];
            float v = acc[no * A2 + o] + dn * h2[(size_t)node * OUTF + o];
            v = fmaf(dn, v, b2[o]);
            float m = v;
#pragma unroll
            for (int mask = 1; mask < 16; mask <<= 1)
                m = fmaxf(m, __shfl_xor(m, mask, 16));
            float ex = __expf(v - m);
            float s  = ex;
#pragma unroll
            for (int mask = 1; mask < 16; mask <<= 1)
                s += __shfl_xor(s, mask, 16);
            out[(size_t)node * OUTF + o] = v - (m + __logf(s));
        }
    }
}

// ----------------------------------------------------------------- launch --
extern "C" void kernel_launch(void* const* d_in, const int* in_sizes, int n_in,
                              void* d_out, int out_size, void* d_ws, size_t ws_size,
                              hipStream_t stream) {
    const float* x  = (const float*)d_in[0];
    const int*   ei = (const int*)d_in[1];    // [2][NE], delivered as int32
    const float* W1 = (const float*)d_in[2];
    const float* b1 = (const float*)d_in[3];
    const float* W2 = (const float*)d_in[4];
    const float* b2 = (const float*)d_in[5];
    float*       out = (float*)d_out;

    char*  ws = (char*)d_ws;
    size_t o  = 0;
    auto alloc = [&](size_t bytes) {
        void* p = ws + o;
        o = (o + bytes + 1023) & ~(size_t)1023;
        return p;
    };
    int*            bcnt  = (int*)           alloc((size_t)NBUCK * 4);
    int*            bbase = (int*)           alloc((size_t)(NBUCK + 1) * 4);
    int*            bcur  = (int*)           alloc((size_t)NBUCK * 4);
    float*          dinv  = (float*)         alloc((size_t)NN * 4);
    unsigned int*   pairs = (unsigned int*)  alloc((size_t)NE * 4);
    unsigned short* h1b   = (unsigned short*)alloc((size_t)NN * HIDF * 2);
    float*          h2    = (float*)         alloc((size_t)NN * OUTF * 4);
    if (o > ws_size) return;   // insufficient scratch -> visible failure

    const int* esrc = ei;
    const int* edst = ei + NE;

    hipMemsetAsync(bcnt, 0, (size_t)NBUCK * 4, stream);

    k_bhist <<<NFB, 256, 0, stream>>>(edst, bcnt);
    k_bscan <<<1, 256, 0, stream>>>(bcnt, bbase, bcur);
    k_fillA <<<NFB, 256, 0, stream>>>(esrc, edst, bcur, pairs);
    k_deg   <<<NBUCK, 256, 0, stream>>>(bbase, pairs, dinv);

    k_gemm1 <<<(NN + GM - 1) / GM, 256, 0, stream>>>(x, W1, h1b);
    k_agg1  <<<NBUCK, 256, 0, stream>>>(bbase, pairs, dinv, h1b, b1, W2, h2);
    k_agg2  <<<NBUCK, 256, 0, stream>>>(bbase, pairs, dinv, h2, b2, out);
}

// Round 13
// 340.812 us; speedup vs baseline: 5.4207x; 5.4207x over previous
//
#include <hip/hip_runtime.h>

#define NN   100000
#define NE   3200000
#define INF_ 512
#define HIDF 64
#define OUTF 16
#define BR    128                       // bucket = 128 consecutive dst nodes
#define NBUCK ((NN + BR - 1) / BR)      // 782
#define EBLK  16384                     // edges per fillA/bhist block
#define NFB   ((NE + EBLK - 1) / EBLK)  // 196

typedef __bf16 bf16x8 __attribute__((ext_vector_type(8)));
typedef float  f32x4  __attribute__((ext_vector_type(4)));

__device__ inline unsigned short f2bfu(float f) {      // RNE fp32 -> bf16 bits
    unsigned u = __builtin_bit_cast(unsigned, f);
    u += 0x7FFFu + ((u >> 16) & 1u);
    return (unsigned short)(u >> 16);
}
__device__ inline __bf16 bfbits(unsigned short h) {
    return __builtin_bit_cast(__bf16, h);
}
__device__ inline float bf2f(unsigned short h) {
    unsigned u = (unsigned)h << 16;
    return __builtin_bit_cast(float, u);
}

// ------------------------------------------------------- bucket histogram --
__global__ __launch_bounds__(256) void k_bhist(const int* __restrict__ dst,
                                               int* __restrict__ bcnt) {
    __shared__ int hist[NBUCK];
    int t = threadIdx.x;
    int e0 = blockIdx.x * EBLK;
    int e1 = (e0 + EBLK < NE) ? e0 + EBLK : NE;
    for (int b = t; b < NBUCK; b += 256) hist[b] = 0;
    __syncthreads();
    for (int e = e0 + t; e < e1; e += 256)
        atomicAdd(&hist[dst[e] >> 7], 1);
    __syncthreads();
    for (int b = t; b < NBUCK; b += 256) {
        int c = hist[b];
        if (c) atomicAdd(&bcnt[b], c);
    }
}

// ----------------------------------------------- bucket scan (one block) ---
__global__ __launch_bounds__(256) void k_bscan(const int* __restrict__ bcnt,
                                               int* __restrict__ bbase,
                                               int* __restrict__ bcur) {
    __shared__ int lds[256];
    int t = threadIdx.x;
    int base = t * 4;
    int c[4];
#pragma unroll
    for (int i = 0; i < 4; ++i) { int idx = base + i; c[i] = idx < NBUCK ? bcnt[idx] : 0; }
    int tsum = c[0] + c[1] + c[2] + c[3];
    lds[t] = tsum;
    __syncthreads();
    for (int off = 1; off < 256; off <<= 1) {
        int v = lds[t];
        int a = (t >= off) ? lds[t - off] : 0;
        __syncthreads();
        lds[t] = v + a;
        __syncthreads();
    }
    int pre = (t == 0) ? 0 : lds[t - 1];
    int run = pre;
#pragma unroll
    for (int i = 0; i < 4; ++i) {
        int idx = base + i;
        if (idx < NBUCK) { bbase[idx] = run; bcur[idx] = run; }
        run += c[i];
    }
    if (t == 255) bbase[NBUCK] = lds[255];   // == NE
}

// -------------------------------------------------- bucketed CSR fill ------
__global__ __launch_bounds__(256) void k_fillA(const int* __restrict__ src,
                                               const int* __restrict__ dst,
                                               int* __restrict__ bcur,
                                               unsigned int* __restrict__ pairs) {
    __shared__ int hist[NBUCK];
    __shared__ int rbase[NBUCK];
    int t = threadIdx.x;
    int e0 = blockIdx.x * EBLK;
    int e1 = (e0 + EBLK < NE) ? e0 + EBLK : NE;

    for (int b = t; b < NBUCK; b += 256) hist[b] = 0;
    __syncthreads();
    for (int e = e0 + t; e < e1; e += 256)
        atomicAdd(&hist[dst[e] >> 7], 1);
    __syncthreads();
    for (int b = t; b < NBUCK; b += 256) {
        int c = hist[b];
        rbase[b] = c ? atomicAdd(&bcur[b], c) : 0;
        hist[b] = 0;
    }
    __syncthreads();
    for (int e = e0 + t; e < e1; e += 256) {
        int s = src[e], d = dst[e];
        int b = d >> 7;
        int slot = atomicAdd(&hist[b], 1);
        pairs[rbase[b] + slot] = ((unsigned)s << 7) | (unsigned)(d & 127);
    }
}

// Pass B: one block per bucket; per-node degree count + scan -> rs, dinv;
// then reorder pairs into csr (writes confined to bucket window).
__global__ __launch_bounds__(256) void k_fillB(const int* __restrict__ bbase,
                                               const unsigned int* __restrict__ pairs,
                                               int* __restrict__ rs,
                                               float* __restrict__ dinv,
                                               int* __restrict__ csr) {
    __shared__ int cnt_s[BR];
    __shared__ int scan_s[BR];
    int b  = blockIdx.x;
    int t  = threadIdx.x;
    int n0 = b * BR;
    int ncount = ((n0 + BR < NN) ? BR : NN - n0);
    int gbase = bbase[b], gend = bbase[b + 1];

    if (t < BR) cnt_s[t] = 0;
    __syncthreads();
    for (int j = gbase + t; j < gend; j += 256)
        atomicAdd(&cnt_s[pairs[j] & 127u], 1);
    __syncthreads();

    int myc = (t < BR) ? cnt_s[t] : 0;
    if (t < BR) scan_s[t] = myc;
    __syncthreads();
#pragma unroll
    for (int off = 1; off < BR; off <<= 1) {
        int a = 0;
        if (t < BR && t >= off) a = scan_s[t - off];
        __syncthreads();
        if (t < BR) scan_s[t] += a;
        __syncthreads();
    }
    if (t < BR) {
        int start = gbase + scan_s[t] - myc;
        if (t < ncount) {
            rs[n0 + t]   = start;
            dinv[n0 + t] = rsqrtf((float)(myc + 1));
        }
        cnt_s[t] = start;
    }
    if (b == NBUCK - 1 && t == 0) rs[NN] = gend;
    __syncthreads();

    for (int j = gbase + t; j < gend; j += 256) {
        unsigned int p = pairs[j];
        int pos = atomicAdd(&cnt_s[p & 127u], 1);
        csr[pos] = (int)(p >> 7);
    }
}

// ---------------------------------------------------------------- GEMM1 -----
// h1b (bf16) = x @ W1 via MFMA 16x16x32 bf16. 4 waves, 64 nodes/block.
#define GM 64

__global__ __launch_bounds__(256) void k_gemm1(const float* __restrict__ x,
                                               const float* __restrict__ W1,
                                               unsigned short* __restrict__ h1b) {
    __shared__ unsigned short w1b[INF_ * 66];   // 66 KB
    int t = threadIdx.x;

#pragma unroll
    for (int i = 0; i < 32; ++i) {
        int fidx = t + i * 256;
        int k  = fidx >> 4;
        int n4 = (fidx & 15) * 4;
        float4 v = *(const float4*)&W1[(size_t)k * HIDF + n4];
        ushort4 u;
        u.x = f2bfu(v.x); u.y = f2bfu(v.y); u.z = f2bfu(v.z); u.w = f2bfu(v.w);
        *(ushort4*)&w1b[k * 66 + n4] = u;
    }
    __syncthreads();

    int lane = t & 63;
    int w    = t >> 6;
    int m    = lane & 15;
    int kg   = lane >> 4;
    int mb   = blockIdx.x * GM;

    int rowi = mb + w * 16 + m;
    size_t xrow = (size_t)((rowi < NN) ? rowi : NN - 1);
    const float* xp = x + xrow * INF_ + kg * 4;

    f32x4 acc0 = {0.f,0.f,0.f,0.f}, acc1 = acc0, acc2 = acc0, acc3 = acc0;

#pragma unroll 2
    for (int ks = 0; ks < 16; ++ks) {
        float4 xa = *(const float4*)(xp + ks * 32);
        float4 xb = *(const float4*)(xp + ks * 32 + 16);
        bf16x8 A;
        A[0] = bfbits(f2bfu(xa.x)); A[1] = bfbits(f2bfu(xa.y));
        A[2] = bfbits(f2bfu(xa.z)); A[3] = bfbits(f2bfu(xa.w));
        A[4] = bfbits(f2bfu(xb.x)); A[5] = bfbits(f2bfu(xb.y));
        A[6] = bfbits(f2bfu(xb.z)); A[7] = bfbits(f2bfu(xb.w));

        const unsigned short* wr = &w1b[(ks * 32 + kg * 4) * 66 + m];
#pragma unroll
        for (int n0t = 0; n0t < 4; ++n0t) {
            const unsigned short* wn = wr + n0t * 16;
            bf16x8 B;
            B[0] = bfbits(wn[0]);        B[1] = bfbits(wn[66]);
            B[2] = bfbits(wn[132]);      B[3] = bfbits(wn[198]);
            B[4] = bfbits(wn[16 * 66]);  B[5] = bfbits(wn[17 * 66]);
            B[6] = bfbits(wn[18 * 66]);  B[7] = bfbits(wn[19 * 66]);
            f32x4 c = (n0t == 0) ? acc0 : (n0t == 1) ? acc1 : (n0t == 2) ? acc2 : acc3;
            c = __builtin_amdgcn_mfma_f32_16x16x32_bf16(A, B, c, 0, 0, 0);
            if      (n0t == 0) acc0 = c;
            else if (n0t == 1) acc1 = c;
            else if (n0t == 2) acc2 = c;
            else               acc3 = c;
        }
    }

#pragma unroll
    for (int r = 0; r < 4; ++r) {
        int node = mb + w * 16 + kg * 4 + r;
        if (node < NN) {
            size_t o = (size_t)node * HIDF + m;
            h1b[o +  0] = f2bfu(acc0[r]);
            h1b[o + 16] = f2bfu(acc1[r]);
            h1b[o + 32] = f2bfu(acc2[r]);
            h1b[o + 48] = f2bfu(acc3[r]);
        }
    }
}

// ------------------- layer1 aggregate + ReLU + fused GEMM2 -----------------
// One wave per dst node (massive TLP), lane = feature. After the aggregate,
// stage the wave's 64 hid values in LDS and compute h2 = hid @ W2 in-wave
// (16 FMA/lane + 2 shuffles). NN % 4 == 0 -> all waves live, barrier safe.
__global__ __launch_bounds__(256) void k_hid2(const int* __restrict__ rs,
                                              const int* __restrict__ csr,
                                              const float* __restrict__ dinv,
                                              const unsigned short* __restrict__ h1b,
                                              const float* __restrict__ b1,
                                              const float* __restrict__ W2,
                                              unsigned short* __restrict__ h2b) {
    __shared__ float w2s[HIDF * OUTF];   // 4 KB
    __shared__ float b1s[HIDF];
    __shared__ float hbuf[4][HIDF];      // per-wave hid row
    int t = threadIdx.x;
    for (int i = t; i < HIDF * OUTF; i += 256) w2s[i] = W2[i];
    if (t < HIDF) b1s[t] = b1[t];
    __syncthreads();

    int f = t & 63;
    int w = t >> 6;
    int n = blockIdx.x * 4 + w;          // NN/4 = 25000 blocks exactly
    int row = rs[n], end = rs[n + 1];
    float dn = dinv[n];
    float acc = dn * bf2f(h1b[(size_t)n * HIDF + f]);   // self-loop

    int j = row;
    for (; j + 4 <= end; j += 4) {
        int s0 = csr[j], s1 = csr[j + 1], s2 = csr[j + 2], s3 = csr[j + 3];
        float w0 = dinv[s0], w1 = dinv[s1], w2 = dinv[s2], w3 = dinv[s3];
        acc = fmaf(bf2f(h1b[(size_t)s0 * HIDF + f]), w0, acc);
        acc = fmaf(bf2f(h1b[(size_t)s1 * HIDF + f]), w1, acc);
        acc = fmaf(bf2f(h1b[(size_t)s2 * HIDF + f]), w2, acc);
        acc = fmaf(bf2f(h1b[(size_t)s3 * HIDF + f]), w3, acc);
    }
    for (; j < end; ++j) {
        int s = csr[j];
        acc = fmaf(bf2f(h1b[(size_t)s * HIDF + f]), dinv[s], acc);
    }
    float hv = fmaxf(fmaf(dn, acc, b1s[f]), 0.f);
    hbuf[w][f] = hv;
    __syncthreads();

    // h2[n][o] = sum_k hid[k] * W2[k][o]; lane l: o = l&15, k-range (l>>4)*16
    int o  = f & 15;
    int kg = f >> 4;
    const float* hb = hbuf[w];
    float s = 0.f;
#pragma unroll
    for (int i = 0; i < 16; ++i) {
        int k = kg * 16 + i;
        s = fmaf(hb[k], w2s[k * OUTF + o], s);
    }
    s += __shfl_xor(s, 16);
    s += __shfl_xor(s, 32);
    if (f < 16) h2b[(size_t)n * OUTF + o] = f2bfu(s);
}

// --------------- layer2 aggregate + bias + log_softmax (bf16 gather) -------
__global__ __launch_bounds__(256) void k_out2(const int* __restrict__ rs,
                                              const int* __restrict__ csr,
                                              const float* __restrict__ dinv,
                                              const unsigned short* __restrict__ h2b,
                                              const float* __restrict__ b2,
                                              float* __restrict__ out) {
    int t = blockIdx.x * 256 + threadIdx.x;
    int n = t >> 4;
    int f = t & 15;
    if (n >= NN) return;
    int row = rs[n], end = rs[n + 1];
    float dn = dinv[n];
    float acc = dn * bf2f(h2b[(size_t)n * OUTF + f]);   // self-loop

    int j = row;
    for (; j + 2 <= end; j += 2) {
        int s0 = csr[j], s1 = csr[j + 1];
        acc = fmaf(bf2f(h2b[(size_t)s0 * OUTF + f]), dinv[s0], acc);
        acc = fmaf(bf2f(h2b[(size_t)s1 * OUTF + f]), dinv[s1], acc);
    }
    for (; j < end; ++j) {
        int s = csr[j];
        acc = fmaf(bf2f(h2b[(size_t)s * OUTF + f]), dinv[s], acc);
    }
    float v = fmaf(dn, acc, b2[f]);

    float m = v;
#pragma unroll
    for (int mask = 1; mask < 16; mask <<= 1)
        m = fmaxf(m, __shfl_xor(m, mask, 16));
    float ex = __expf(v - m);
    float s  = ex;
#pragma unroll
    for (int mask = 1; mask < 16; mask <<= 1)
        s += __shfl_xor(s, mask, 16);
    out[(size_t)n * OUTF + f] = v - (m + __logf(s));
}

// ----------------------------------------------------------------- launch --
extern "C" void kernel_launch(void* const* d_in, const int* in_sizes, int n_in,
                              void* d_out, int out_size, void* d_ws, size_t ws_size,
                              hipStream_t stream) {
    const float* x  = (const float*)d_in[0];
    const int*   ei = (const int*)d_in[1];    // [2][NE], delivered as int32
    const float* W1 = (const float*)d_in[2];
    const float* b1 = (const float*)d_in[3];
    const float* W2 = (const float*)d_in[4];
    const float* b2 = (const float*)d_in[5];
    float*       out = (float*)d_out;

    char*  ws = (char*)d_ws;
    size_t o  = 0;
    auto alloc = [&](size_t bytes) {
        void* p = ws + o;
        o = (o + bytes + 1023) & ~(size_t)1023;
        return p;
    };
    int*            bcnt  = (int*)           alloc((size_t)NBUCK * 4);
    int*            bbase = (int*)           alloc((size_t)(NBUCK + 1) * 4);
    int*            bcur  = (int*)           alloc((size_t)NBUCK * 4);
    int*            rs    = (int*)           alloc((size_t)(NN + 1) * 4);
    int*            csr   = (int*)           alloc((size_t)NE * 4);
    float*          dinv  = (float*)         alloc((size_t)NN * 4);
    unsigned int*   pairs = (unsigned int*)  alloc((size_t)NE * 4);
    unsigned short* h1b   = (unsigned short*)alloc((size_t)NN * HIDF * 2);
    unsigned short* h2b   = (unsigned short*)alloc((size_t)NN * OUTF * 2);
    if (o > ws_size) return;   // insufficient scratch -> visible failure

    const int* esrc = ei;
    const int* edst = ei + NE;

    hipMemsetAsync(bcnt, 0, (size_t)NBUCK * 4, stream);

    k_bhist <<<NFB, 256, 0, stream>>>(edst, bcnt);
    k_bscan <<<1, 256, 0, stream>>>(bcnt, bbase, bcur);
    k_fillA <<<NFB, 256, 0, stream>>>(esrc, edst, bcur, pairs);
    k_fillB <<<NBUCK, 256, 0, stream>>>(bbase, pairs, rs, dinv, csr);

    k_gemm1 <<<(NN + GM - 1) / GM, 256, 0, stream>>>(x, W1, h1b);
    k_hid2  <<<NN / 4, 256, 0, stream>>>(rs, csr, dinv, h1b, b1, W2, h2b);
    k_out2  <<<(NN * OUTF + 255) / 256, 256, 0, stream>>>(rs, csr, dinv, h2b, b2, out);
}

// Round 14
// 303.245 us; speedup vs baseline: 6.0922x; 1.1239x over previous
//
#include <hip/hip_runtime.h>

#define NN   100000
#define NE   3200000
#define INF_ 512
#define HIDF 64
#define OUTF 16
#define BR    128                       // bucket = 128 consecutive dst nodes
#define NBUCK ((NN + BR - 1) / BR)      // 782
#define EBLK  16384                     // edges per fillA/bhist block
#define NFB   ((NE + EBLK - 1) / EBLK)  // 196

typedef __bf16 bf16x8 __attribute__((ext_vector_type(8)));
typedef float  f32x4  __attribute__((ext_vector_type(4)));

__device__ inline unsigned short f2bfu(float f) {      // RNE fp32 -> bf16 bits
    unsigned u = __builtin_bit_cast(unsigned, f);
    u += 0x7FFFu + ((u >> 16) & 1u);
    return (unsigned short)(u >> 16);
}
__device__ inline __bf16 bfbits(unsigned short h) {
    return __builtin_bit_cast(__bf16, h);
}
__device__ inline float bf2f(unsigned short h) {
    unsigned u = (unsigned)h << 16;
    return __builtin_bit_cast(float, u);
}

// ------------------------------------------------------- bucket histogram --
__global__ __launch_bounds__(256) void k_bhist(const int* __restrict__ dst,
                                               int* __restrict__ bcnt) {
    __shared__ int hist[NBUCK];
    int t = threadIdx.x;
    int e0 = blockIdx.x * EBLK;
    int e1 = (e0 + EBLK < NE) ? e0 + EBLK : NE;
    for (int b = t; b < NBUCK; b += 256) hist[b] = 0;
    __syncthreads();
    for (int e = e0 + t; e < e1; e += 256)
        atomicAdd(&hist[dst[e] >> 7], 1);
    __syncthreads();
    for (int b = t; b < NBUCK; b += 256) {
        int c = hist[b];
        if (c) atomicAdd(&bcnt[b], c);
    }
}

// ----------------------------------------------- bucket scan (one block) ---
__global__ __launch_bounds__(256) void k_bscan(const int* __restrict__ bcnt,
                                               int* __restrict__ bbase,
                                               int* __restrict__ bcur) {
    __shared__ int lds[256];
    int t = threadIdx.x;
    int base = t * 4;
    int c[4];
#pragma unroll
    for (int i = 0; i < 4; ++i) { int idx = base + i; c[i] = idx < NBUCK ? bcnt[idx] : 0; }
    int tsum = c[0] + c[1] + c[2] + c[3];
    lds[t] = tsum;
    __syncthreads();
    for (int off = 1; off < 256; off <<= 1) {
        int v = lds[t];
        int a = (t >= off) ? lds[t - off] : 0;
        __syncthreads();
        lds[t] = v + a;
        __syncthreads();
    }
    int pre = (t == 0) ? 0 : lds[t - 1];
    int run = pre;
#pragma unroll
    for (int i = 0; i < 4; ++i) {
        int idx = base + i;
        if (idx < NBUCK) { bbase[idx] = run; bcur[idx] = run; }
        run += c[i];
    }
    if (t == 255) bbase[NBUCK] = lds[255];   // == NE
}

// -------------------------------------------------- bucketed CSR fill ------
__global__ __launch_bounds__(256) void k_fillA(const int* __restrict__ src,
                                               const int* __restrict__ dst,
                                               int* __restrict__ bcur,
                                               unsigned int* __restrict__ pairs) {
    __shared__ int hist[NBUCK];
    __shared__ int rbase[NBUCK];
    int t = threadIdx.x;
    int e0 = blockIdx.x * EBLK;
    int e1 = (e0 + EBLK < NE) ? e0 + EBLK : NE;

    for (int b = t; b < NBUCK; b += 256) hist[b] = 0;
    __syncthreads();
    for (int e = e0 + t; e < e1; e += 256)
        atomicAdd(&hist[dst[e] >> 7], 1);
    __syncthreads();
    for (int b = t; b < NBUCK; b += 256) {
        int c = hist[b];
        rbase[b] = c ? atomicAdd(&bcur[b], c) : 0;
        hist[b] = 0;
    }
    __syncthreads();
    for (int e = e0 + t; e < e1; e += 256) {
        int s = src[e], d = dst[e];
        int b = d >> 7;
        int slot = atomicAdd(&hist[b], 1);
        pairs[rbase[b] + slot] = ((unsigned)s << 7) | (unsigned)(d & 127);
    }
}

// Pass B: one block per bucket; per-node degree count + scan -> rs, dinv;
// then reorder pairs into csr (writes confined to bucket window).
__global__ __launch_bounds__(256) void k_fillB(const int* __restrict__ bbase,
                                               const unsigned int* __restrict__ pairs,
                                               int* __restrict__ rs,
                                               float* __restrict__ dinv,
                                               int* __restrict__ csr) {
    __shared__ int cnt_s[BR];
    __shared__ int scan_s[BR];
    int b  = blockIdx.x;
    int t  = threadIdx.x;
    int n0 = b * BR;
    int ncount = ((n0 + BR < NN) ? BR : NN - n0);
    int gbase = bbase[b], gend = bbase[b + 1];

    if (t < BR) cnt_s[t] = 0;
    __syncthreads();
    for (int j = gbase + t; j < gend; j += 256)
        atomicAdd(&cnt_s[pairs[j] & 127u], 1);
    __syncthreads();

    int myc = (t < BR) ? cnt_s[t] : 0;
    if (t < BR) scan_s[t] = myc;
    __syncthreads();
#pragma unroll
    for (int off = 1; off < BR; off <<= 1) {
        int a = 0;
        if (t < BR && t >= off) a = scan_s[t - off];
        __syncthreads();
        if (t < BR) scan_s[t] += a;
        __syncthreads();
    }
    if (t < BR) {
        int start = gbase + scan_s[t] - myc;
        if (t < ncount) {
            rs[n0 + t]   = start;
            dinv[n0 + t] = rsqrtf((float)(myc + 1));
        }
        cnt_s[t] = start;
    }
    if (b == NBUCK - 1 && t == 0) rs[NN] = gend;
    __syncthreads();

    for (int j = gbase + t; j < gend; j += 256) {
        unsigned int p = pairs[j];
        int pos = atomicAdd(&cnt_s[p & 127u], 1);
        csr[pos] = (int)(p >> 7);
    }
}

// ---------------------------------------------------------------- GEMM1 -----
// h1s (bf16) = dinv[n] * (x @ W1)[n]  via MFMA 16x16x32 bf16.
// Pre-scaling by dinv makes the aggregation loops pure adds (no per-src dinv).
#define GM 64

__global__ __launch_bounds__(256) void k_gemm1(const float* __restrict__ x,
                                               const float* __restrict__ W1,
                                               const float* __restrict__ dinv,
                                               unsigned short* __restrict__ h1s) {
    __shared__ unsigned short w1b[INF_ * 66];   // 66 KB
    int t = threadIdx.x;

#pragma unroll
    for (int i = 0; i < 32; ++i) {
        int fidx = t + i * 256;
        int k  = fidx >> 4;
        int n4 = (fidx & 15) * 4;
        float4 v = *(const float4*)&W1[(size_t)k * HIDF + n4];
        ushort4 u;
        u.x = f2bfu(v.x); u.y = f2bfu(v.y); u.z = f2bfu(v.z); u.w = f2bfu(v.w);
        *(ushort4*)&w1b[k * 66 + n4] = u;
    }
    __syncthreads();

    int lane = t & 63;
    int w    = t >> 6;
    int m    = lane & 15;
    int kg   = lane >> 4;
    int mb   = blockIdx.x * GM;

    int rowi = mb + w * 16 + m;
    size_t xrow = (size_t)((rowi < NN) ? rowi : NN - 1);
    const float* xp = x + xrow * INF_ + kg * 4;

    f32x4 acc0 = {0.f,0.f,0.f,0.f}, acc1 = acc0, acc2 = acc0, acc3 = acc0;

#pragma unroll 2
    for (int ks = 0; ks < 16; ++ks) {
        float4 xa = *(const float4*)(xp + ks * 32);
        float4 xb = *(const float4*)(xp + ks * 32 + 16);
        bf16x8 A;
        A[0] = bfbits(f2bfu(xa.x)); A[1] = bfbits(f2bfu(xa.y));
        A[2] = bfbits(f2bfu(xa.z)); A[3] = bfbits(f2bfu(xa.w));
        A[4] = bfbits(f2bfu(xb.x)); A[5] = bfbits(f2bfu(xb.y));
        A[6] = bfbits(f2bfu(xb.z)); A[7] = bfbits(f2bfu(xb.w));

        const unsigned short* wr = &w1b[(ks * 32 + kg * 4) * 66 + m];
#pragma unroll
        for (int n0t = 0; n0t < 4; ++n0t) {
            const unsigned short* wn = wr + n0t * 16;
            bf16x8 B;
            B[0] = bfbits(wn[0]);        B[1] = bfbits(wn[66]);
            B[2] = bfbits(wn[132]);      B[3] = bfbits(wn[198]);
            B[4] = bfbits(wn[16 * 66]);  B[5] = bfbits(wn[17 * 66]);
            B[6] = bfbits(wn[18 * 66]);  B[7] = bfbits(wn[19 * 66]);
            f32x4 c = (n0t == 0) ? acc0 : (n0t == 1) ? acc1 : (n0t == 2) ? acc2 : acc3;
            c = __builtin_amdgcn_mfma_f32_16x16x32_bf16(A, B, c, 0, 0, 0);
            if      (n0t == 0) acc0 = c;
            else if (n0t == 1) acc1 = c;
            else if (n0t == 2) acc2 = c;
            else               acc3 = c;
        }
    }

#pragma unroll
    for (int r = 0; r < 4; ++r) {
        int node = mb + w * 16 + kg * 4 + r;
        if (node < NN) {
            float dv = dinv[node];
            size_t o = (size_t)node * HIDF + m;
            h1s[o +  0] = f2bfu(acc0[r] * dv);
            h1s[o + 16] = f2bfu(acc1[r] * dv);
            h1s[o + 32] = f2bfu(acc2[r] * dv);
            h1s[o + 48] = f2bfu(acc3[r] * dv);
        }
    }
}

// ------------------- layer1 aggregate + ReLU + fused GEMM2 -----------------
// One wave per dst node; lane = feature. n hoisted to SGPR (readfirstlane) so
// row/end/dn/csr loads are scalar. Inner loop: pure bf16-gather + add.
// Epilogue stores h2s = dinv[n] * h2 (bf16) so out2's loop is also add-only.
__global__ __launch_bounds__(256) void k_hid2(const int* __restrict__ rs,
                                              const int* __restrict__ csr,
                                              const float* __restrict__ dinv,
                                              const unsigned short* __restrict__ h1s,
                                              const float* __restrict__ b1,
                                              const float* __restrict__ W2,
                                              unsigned short* __restrict__ h2s) {
    __shared__ float w2s[HIDF * OUTF];   // 4 KB
    __shared__ float b1s[HIDF];
    __shared__ float hbuf[4][HIDF];      // per-wave hid row
    int t = threadIdx.x;
    for (int i = t; i < HIDF * OUTF; i += 256) w2s[i] = W2[i];
    if (t < HIDF) b1s[t] = b1[t];
    __syncthreads();

    int f = t & 63;
    int w = t >> 6;
    int n = __builtin_amdgcn_readfirstlane(blockIdx.x * 4 + w);   // SGPR node id
    int row = rs[n], end = rs[n + 1];
    float dn = dinv[n];
    float acc = bf2f(h1s[(size_t)n * HIDF + f]);   // self-loop (pre-scaled)

    int j = row;
    for (; j + 4 <= end; j += 4) {
        int s0 = csr[j], s1 = csr[j + 1], s2 = csr[j + 2], s3 = csr[j + 3];
        acc += bf2f(h1s[(size_t)s0 * HIDF + f]);
        acc += bf2f(h1s[(size_t)s1 * HIDF + f]);
        acc += bf2f(h1s[(size_t)s2 * HIDF + f]);
        acc += bf2f(h1s[(size_t)s3 * HIDF + f]);
    }
    for (; j < end; ++j)
        acc += bf2f(h1s[(size_t)csr[j] * HIDF + f]);

    float hv = fmaxf(fmaf(dn, acc, b1s[f]), 0.f);
    hbuf[w][f] = hv;
    __syncthreads();

    // h2[n][o] = sum_k hid[k] * W2[k][o]; lane l: o = l&15, k-range (l>>4)*16
    int o  = f & 15;
    int kg = f >> 4;
    const float* hb = hbuf[w];
    float s = 0.f;
#pragma unroll
    for (int i = 0; i < 16; ++i) {
        int k = kg * 16 + i;
        s = fmaf(hb[k], w2s[k * OUTF + o], s);
    }
    s += __shfl_xor(s, 16);
    s += __shfl_xor(s, 32);
    if (f < 16) h2s[(size_t)n * OUTF + o] = f2bfu(dn * s);   // pre-scaled
}

// --------------- layer2 aggregate + bias + log_softmax (pre-scaled) --------
__global__ __launch_bounds__(256) void k_out2(const int* __restrict__ rs,
                                              const int* __restrict__ csr,
                                              const float* __restrict__ dinv,
                                              const unsigned short* __restrict__ h2s,
                                              const float* __restrict__ b2,
                                              float* __restrict__ out) {
    int t = blockIdx.x * 256 + threadIdx.x;
    int n = t >> 4;
    int f = t & 15;
    if (n >= NN) return;
    int row = rs[n], end = rs[n + 1];
    float dn = dinv[n];
    float acc = bf2f(h2s[(size_t)n * OUTF + f]);   // self-loop (pre-scaled)

    int j = row;
    for (; j + 2 <= end; j += 2) {
        int s0 = csr[j], s1 = csr[j + 1];
        acc += bf2f(h2s[(size_t)s0 * OUTF + f]);
        acc += bf2f(h2s[(size_t)s1 * OUTF + f]);
    }
    for (; j < end; ++j)
        acc += bf2f(h2s[(size_t)csr[j] * OUTF + f]);

    float v = fmaf(dn, acc, b2[f]);

    float m = v;
#pragma unroll
    for (int mask = 1; mask < 16; mask <<= 1)
        m = fmaxf(m, __shfl_xor(m, mask, 16));
    float ex = __expf(v - m);
    float s  = ex;
#pragma unroll
    for (int mask = 1; mask < 16; mask <<= 1)
        s += __shfl_xor(s, mask, 16);
    out[(size_t)n * OUTF + f] = v - (m + __logf(s));
}

// ----------------------------------------------------------------- launch --
extern "C" void kernel_launch(void* const* d_in, const int* in_sizes, int n_in,
                              void* d_out, int out_size, void* d_ws, size_t ws_size,
                              hipStream_t stream) {
    const float* x  = (const float*)d_in[0];
    const int*   ei = (const int*)d_in[1];    // [2][NE], delivered as int32
    const float* W1 = (const float*)d_in[2];
    const float* b1 = (const float*)d_in[3];
    const float* W2 = (const float*)d_in[4];
    const float* b2 = (const float*)d_in[5];
    float*       out = (float*)d_out;

    char*  ws = (char*)d_ws;
    size_t o  = 0;
    auto alloc = [&](size_t bytes) {
        void* p = ws + o;
        o = (o + bytes + 1023) & ~(size_t)1023;
        return p;
    };
    int*            bcnt  = (int*)           alloc((size_t)NBUCK * 4);
    int*            bbase = (int*)           alloc((size_t)(NBUCK + 1) * 4);
    int*            bcur  = (int*)           alloc((size_t)NBUCK * 4);
    int*            rs    = (int*)           alloc((size_t)(NN + 1) * 4);
    int*            csr   = (int*)           alloc((size_t)NE * 4);
    float*          dinv  = (float*)         alloc((size_t)NN * 4);
    unsigned int*   pairs = (unsigned int*)  alloc((size_t)NE * 4);
    unsigned short* h1s   = (unsigned short*)alloc((size_t)NN * HIDF * 2);
    unsigned short* h2s   = (unsigned short*)alloc((size_t)NN * OUTF * 2);
    if (o > ws_size) return;   // insufficient scratch -> visible failure

    const int* esrc = ei;
    const int* edst = ei + NE;

    hipMemsetAsync(bcnt, 0, (size_t)NBUCK * 4, stream);

    k_bhist <<<NFB, 256, 0, stream>>>(edst, bcnt);
    k_bscan <<<1, 256, 0, stream>>>(bcnt, bbase, bcur);
    k_fillA <<<NFB, 256, 0, stream>>>(esrc, edst, bcur, pairs);
    k_fillB <<<NBUCK, 256, 0, stream>>>(bbase, pairs, rs, dinv, csr);

    k_gemm1 <<<(NN + GM - 1) / GM, 256, 0, stream>>>(x, W1, dinv, h1s);
    k_hid2  <<<NN / 4, 256, 0, stream>>>(rs, csr, dinv, h1s, b1, W2, h2s);
    k_out2  <<<(NN * OUTF + 255) / 256, 256, 0, stream>>>(rs, csr, dinv, h2s, b2, out);
}

// Round 16
// 266.885 us; speedup vs baseline: 6.9222x; 1.1362x over previous
//
#include <hip/hip_runtime.h>

#define NN   100000
#define NE   3200000
#define INF_ 512
#define HIDF 64
#define OUTF 16
#define BR    128                       // bucket = 128 consecutive dst nodes
#define NBUCK ((NN + BR - 1) / BR)      // 782
#define BSLOT 4864                      // static region/bucket; λ=4092, +12σ
#define EBLK  16384                     // edges per fillA block
#define NFB   ((NE + EBLK - 1) / EBLK)  // 196

typedef __bf16 bf16x8 __attribute__((ext_vector_type(8)));
typedef float  f32x4  __attribute__((ext_vector_type(4)));

__device__ inline unsigned short f2bfu(float f) {      // RNE fp32 -> bf16 bits
    unsigned u = __builtin_bit_cast(unsigned, f);
    u += 0x7FFFu + ((u >> 16) & 1u);
    return (unsigned short)(u >> 16);
}
__device__ inline __bf16 bfbits(unsigned short h) {
    return __builtin_bit_cast(__bf16, h);
}
__device__ inline float bf2f(unsigned short h) {
    unsigned u = (unsigned)h << 16;
    return __builtin_bit_cast(float, u);
}

// ----------------------------------------------------- bucket cursor init --
__global__ __launch_bounds__(256) void k_binit(int* __restrict__ bcur) {
    int b = blockIdx.x * 256 + threadIdx.x;
    if (b < NBUCK) bcur[b] = b * BSLOT;
}

// -------------------------------------------------- bucketed pair fill -----
// Block-local histogram + bulk reservation into STATIC per-bucket regions.
// Packed pair = (src<<7)|(dst&127).
__global__ __launch_bounds__(256) void k_fillA(const int* __restrict__ src,
                                               const int* __restrict__ dst,
                                               int* __restrict__ bcur,
                                               unsigned int* __restrict__ pairs) {
    __shared__ int hist[NBUCK];
    __shared__ int rbase[NBUCK];
    int t = threadIdx.x;
    int e0 = blockIdx.x * EBLK;
    int e1 = (e0 + EBLK < NE) ? e0 + EBLK : NE;

    for (int b = t; b < NBUCK; b += 256) hist[b] = 0;
    __syncthreads();
    for (int e = e0 + t; e < e1; e += 256)
        atomicAdd(&hist[dst[e] >> 7], 1);
    __syncthreads();
    for (int b = t; b < NBUCK; b += 256) {
        int c = hist[b];
        rbase[b] = c ? atomicAdd(&bcur[b], c) : 0;
        hist[b] = 0;
    }
    __syncthreads();
    for (int e = e0 + t; e < e1; e += 256) {
        int s = src[e], d = dst[e];
        int b = d >> 7;
        int slot = atomicAdd(&hist[b], 1);
        pairs[rbase[b] + slot] = ((unsigned)s << 7) | (unsigned)(d & 127);
    }
}

// Pass B: one block per bucket. Per-node degree count + scan -> rs/re/dinv;
// reorder pairs into csr (all writes confined to the bucket's static window).
__global__ __launch_bounds__(256) void k_fillB(const int* __restrict__ bcur,
                                               const unsigned int* __restrict__ pairs,
                                               int* __restrict__ rs,
                                               int* __restrict__ re,
                                               float* __restrict__ dinv,
                                               int* __restrict__ csr) {
    __shared__ int cnt_s[BR];
    __shared__ int scan_s[BR];
    int b  = blockIdx.x;
    int t  = threadIdx.x;
    int n0 = b * BR;
    int ncount = ((n0 + BR < NN) ? BR : NN - n0);
    int gbase = b * BSLOT;
    int gend  = bcur[b];          // gbase + edges-in-bucket

    if (t < BR) cnt_s[t] = 0;
    __syncthreads();
    for (int j = gbase + t; j < gend; j += 256)
        atomicAdd(&cnt_s[pairs[j] & 127u], 1);
    __syncthreads();

    int myc = (t < BR) ? cnt_s[t] : 0;
    if (t < BR) scan_s[t] = myc;
    __syncthreads();
#pragma unroll
    for (int off = 1; off < BR; off <<= 1) {
        int a = 0;
        if (t < BR && t >= off) a = scan_s[t - off];
        __syncthreads();
        if (t < BR) scan_s[t] += a;
        __syncthreads();
    }
    if (t < BR) {
        int start = gbase + scan_s[t] - myc;
        if (t < ncount) {
            rs[n0 + t]   = start;
            re[n0 + t]   = start + myc;
            dinv[n0 + t] = rsqrtf((float)(myc + 1));
        }
        cnt_s[t] = start;
    }
    __syncthreads();

    for (int j = gbase + t; j < gend; j += 256) {
        unsigned int p = pairs[j];
        int pos = atomicAdd(&cnt_s[p & 127u], 1);
        csr[pos] = (int)(p >> 7);
    }
}

// ---------------------------------------------------------------- GEMM1 -----
// h1s (bf16) = dinv[n] * (x @ W1)[n]  via MFMA 16x16x32 bf16.
#define GM 64

__global__ __launch_bounds__(256) void k_gemm1(const float* __restrict__ x,
                                               const float* __restrict__ W1,
                                               const float* __restrict__ dinv,
                                               unsigned short* __restrict__ h1s) {
    __shared__ unsigned short w1b[INF_ * 66];   // 66 KB
    int t = threadIdx.x;

#pragma unroll
    for (int i = 0; i < 32; ++i) {
        int fidx = t + i * 256;
        int k  = fidx >> 4;
        int n4 = (fidx & 15) * 4;
        float4 v = *(const float4*)&W1[(size_t)k * HIDF + n4];
        ushort4 u;
        u.x = f2bfu(v.x); u.y = f2bfu(v.y); u.z = f2bfu(v.z); u.w = f2bfu(v.w);
        *(ushort4*)&w1b[k * 66 + n4] = u;
    }
    __syncthreads();

    int lane = t & 63;
    int w    = t >> 6;
    int m    = lane & 15;
    int kg   = lane >> 4;
    int mb   = blockIdx.x * GM;

    int rowi = mb + w * 16 + m;
    size_t xrow = (size_t)((rowi < NN) ? rowi : NN - 1);
    const float* xp = x + xrow * INF_ + kg * 4;

    f32x4 acc0 = {0.f,0.f,0.f,0.f}, acc1 = acc0, acc2 = acc0, acc3 = acc0;

#pragma unroll 2
    for (int ks = 0; ks < 16; ++ks) {
        float4 xa = *(const float4*)(xp + ks * 32);
        float4 xb = *(const float4*)(xp + ks * 32 + 16);
        bf16x8 A;
        A[0] = bfbits(f2bfu(xa.x)); A[1] = bfbits(f2bfu(xa.y));
        A[2] = bfbits(f2bfu(xa.z)); A[3] = bfbits(f2bfu(xa.w));
        A[4] = bfbits(f2bfu(xb.x)); A[5] = bfbits(f2bfu(xb.y));
        A[6] = bfbits(f2bfu(xb.z)); A[7] = bfbits(f2bfu(xb.w));

        const unsigned short* wr = &w1b[(ks * 32 + kg * 4) * 66 + m];
#pragma unroll
        for (int n0t = 0; n0t < 4; ++n0t) {
            const unsigned short* wn = wr + n0t * 16;
            bf16x8 B;
            B[0] = bfbits(wn[0]);        B[1] = bfbits(wn[66]);
            B[2] = bfbits(wn[132]);      B[3] = bfbits(wn[198]);
            B[4] = bfbits(wn[16 * 66]);  B[5] = bfbits(wn[17 * 66]);
            B[6] = bfbits(wn[18 * 66]);  B[7] = bfbits(wn[19 * 66]);
            f32x4 c = (n0t == 0) ? acc0 : (n0t == 1) ? acc1 : (n0t == 2) ? acc2 : acc3;
            c = __builtin_amdgcn_mfma_f32_16x16x32_bf16(A, B, c, 0, 0, 0);
            if      (n0t == 0) acc0 = c;
            else if (n0t == 1) acc1 = c;
            else if (n0t == 2) acc2 = c;
            else               acc3 = c;
        }
    }

#pragma unroll
    for (int r = 0; r < 4; ++r) {
        int node = mb + w * 16 + kg * 4 + r;
        if (node < NN) {
            float dv = dinv[node];
            size_t o = (size_t)node * HIDF + m;
            h1s[o +  0] = f2bfu(acc0[r] * dv);
            h1s[o + 16] = f2bfu(acc1[r] * dv);
            h1s[o + 32] = f2bfu(acc2[r] * dv);
            h1s[o + 48] = f2bfu(acc3[r] * dv);
        }
    }
}

// ------------------- layer1 aggregate + ReLU + fused GEMM2 -----------------
// One wave per dst node; lane = feature. n/rs/re/csr in SGPRs; u32 gather
// indices (single v_lshl_add addr); 8 independent gathers in flight.
__global__ __launch_bounds__(256) void k_hid2(const int* __restrict__ rs,
                                              const int* __restrict__ re,
                                              const int* __restrict__ csr,
                                              const float* __restrict__ dinv,
                                              const unsigned short* __restrict__ h1s,
                                              const float* __restrict__ b1,
                                              const float* __restrict__ W2,
                                              unsigned short* __restrict__ h2s) {
    __shared__ float w2s[HIDF * OUTF];   // 4 KB
    __shared__ float b1s[HIDF];
    __shared__ float hbuf[4][HIDF];
    int t = threadIdx.x;
    for (int i = t; i < HIDF * OUTF; i += 256) w2s[i] = W2[i];
    if (t < HIDF) b1s[t] = b1[t];
    __syncthreads();

    int f = t & 63;
    int w = t >> 6;
    int n = __builtin_amdgcn_readfirstlane(blockIdx.x * 4 + w);   // SGPR
    int row = rs[n], end = re[n];
    float dn = dinv[n];
    float acc = bf2f(h1s[(unsigned)(n * HIDF + f)]);   // self (pre-scaled)

    int j = row;
    for (; j + 8 <= end; j += 8) {
        int s0 = csr[j],     s1 = csr[j + 1], s2 = csr[j + 2], s3 = csr[j + 3];
        int s4 = csr[j + 4], s5 = csr[j + 5], s6 = csr[j + 6], s7 = csr[j + 7];
        float v0 = bf2f(h1s[(unsigned)(s0 * HIDF + f)]);
        float v1 = bf2f(h1s[(unsigned)(s1 * HIDF + f)]);
        float v2 = bf2f(h1s[(unsigned)(s2 * HIDF + f)]);
        float v3 = bf2f(h1s[(unsigned)(s3 * HIDF + f)]);
        float v4 = bf2f(h1s[(unsigned)(s4 * HIDF + f)]);
        float v5 = bf2f(h1s[(unsigned)(s5 * HIDF + f)]);
        float v6 = bf2f(h1s[(unsigned)(s6 * HIDF + f)]);
        float v7 = bf2f(h1s[(unsigned)(s7 * HIDF + f)]);
        acc += ((v0 + v1) + (v2 + v3)) + ((v4 + v5) + (v6 + v7));
    }
    for (; j < end; ++j)
        acc += bf2f(h1s[(unsigned)(csr[j] * HIDF + f)]);

    float hv = fmaxf(fmaf(dn, acc, b1s[f]), 0.f);
    hbuf[w][f] = hv;
    __syncthreads();

    // h2[n][o] = sum_k hid[k] * W2[k][o]; lane l: o = l&15, k-range (l>>4)*16
    int o  = f & 15;
    int kg = f >> 4;
    const float* hb = hbuf[w];
    float s = 0.f;
#pragma unroll
    for (int i = 0; i < 16; ++i) {
        int k = kg * 16 + i;
        s = fmaf(hb[k], w2s[k * OUTF + o], s);
    }
    s += __shfl_xor(s, 16);
    s += __shfl_xor(s, 32);
    if (f < 16) h2s[(unsigned)(n * OUTF + o)] = f2bfu(dn * s);   // pre-scaled
}

// --------------- layer2 aggregate + bias + log_softmax (pre-scaled) --------
__global__ __launch_bounds__(256) void k_out2(const int* __restrict__ rs,
                                              const int* __restrict__ re,
                                              const int* __restrict__ csr,
                                              const float* __restrict__ dinv,
                                              const unsigned short* __restrict__ h2s,
                                              const float* __restrict__ b2,
                                              float* __restrict__ out) {
    int t = blockIdx.x * 256 + threadIdx.x;
    int n = t >> 4;
    int f = t & 15;
    if (n >= NN) return;
    int row = rs[n], end = re[n];
    float dn = dinv[n];
    float acc = bf2f(h2s[(unsigned)(n * OUTF + f)]);   // self (pre-scaled)

    int j = row;
    for (; j + 4 <= end; j += 4) {
        int s0 = csr[j], s1 = csr[j + 1], s2 = csr[j + 2], s3 = csr[j + 3];
        float v0 = bf2f(h2s[(unsigned)(s0 * OUTF + f)]);
        float v1 = bf2f(h2s[(unsigned)(s1 * OUTF + f)]);
        float v2 = bf2f(h2s[(unsigned)(s2 * OUTF + f)]);
        float v3 = bf2f(h2s[(unsigned)(s3 * OUTF + f)]);
        acc += (v0 + v1) + (v2 + v3);
    }
    for (; j < end; ++j)
        acc += bf2f(h2s[(unsigned)(csr[j] * OUTF + f)]);

    float v = fmaf(dn, acc, b2[f]);

    float m = v;
#pragma unroll
    for (int mask = 1; mask < 16; mask <<= 1)
        m = fmaxf(m, __shfl_xor(m, mask, 16));
    float ex = __expf(v - m);
    float s  = ex;
#pragma unroll
    for (int mask = 1; mask < 16; mask <<= 1)
        s += __shfl_xor(s, mask, 16);
    out[(size_t)n * OUTF + f] = v - (m + __logf(s));
}

// ----------------------------------------------------------------- launch --
extern "C" void kernel_launch(void* const* d_in, const int* in_sizes, int n_in,
                              void* d_out, int out_size, void* d_ws, size_t ws_size,
                              hipStream_t stream) {
    const float* x  = (const float*)d_in[0];
    const int*   ei = (const int*)d_in[1];    // [2][NE], delivered as int32
    const float* W1 = (const float*)d_in[2];
    const float* b1 = (const float*)d_in[3];
    const float* W2 = (const float*)d_in[4];
    const float* b2 = (const float*)d_in[5];
    float*       out = (float*)d_out;

    char*  ws = (char*)d_ws;
    size_t o  = 0;
    auto alloc = [&](size_t bytes) {
        void* p = ws + o;
        o = (o + bytes + 1023) & ~(size_t)1023;
        return p;
    };
    int*            bcur  = (int*)           alloc((size_t)NBUCK * 4);
    int*            rs    = (int*)           alloc((size_t)NN * 4);
    int*            re    = (int*)           alloc((size_t)NN * 4);
    int*            csr   = (int*)           alloc((size_t)NBUCK * BSLOT * 4);
    unsigned int*   pairs = (unsigned int*)  alloc((size_t)NBUCK * BSLOT * 4);
    float*          dinv  = (float*)         alloc((size_t)NN * 4);
    unsigned short* h1s   = (unsigned short*)alloc((size_t)NN * HIDF * 2);
    unsigned short* h2s   = (unsigned short*)alloc((size_t)NN * OUTF * 2);
    if (o > ws_size) return;   // insufficient scratch -> visible failure

    const int* esrc = ei;
    const int* edst = ei + NE;

    k_binit <<<(NBUCK + 255) / 256, 256, 0, stream>>>(bcur);
    k_fillA <<<NFB, 256, 0, stream>>>(esrc, edst, bcur, pairs);
    k_fillB <<<NBUCK, 256, 0, stream>>>(bcur, pairs, rs, re, dinv, csr);

    k_gemm1 <<<(NN + GM - 1) / GM, 256, 0, stream>>>(x, W1, dinv, h1s);
    k_hid2  <<<NN / 4, 256, 0, stream>>>(rs, re, csr, dinv, h1s, b1, W2, h2s);
    k_out2  <<<(NN * OUTF + 255) / 256, 256, 0, stream>>>(rs, re, csr, dinv, h2s, b2, out);
}